// Round 1
// baseline (175.678 us; speedup 1.0000x reference)
//
#include <hip/hip_runtime.h>

#define HW      (1024 * 1024)
#define HW4     (HW / 4)
#define NBINS   4096
#define NIMG    9                 // 8 input images + 1 style
#define BPI     64                // blocks per image
#define THREADS 256
#define F4_PER_BLOCK (HW4 / BPI)  // 4096 float4 elements per block per channel

// Exact replica of searchsorted(boundaries, x, side='left') with
// boundaries b_j = (j+1)*0.125 - 1 (j = 0..14), i.e. idx = #{ b_j < x }.
// Branchless binary search with exact float compares (all boundary values
// k/8 - 1 are exactly representable), so binning matches the reference
// bit-for-bit -- no floor()/rounding tie hazards.
__device__ __forceinline__ int bin16(float x) {
    int lo = 0;
    if (0.0f < x) lo = 8;                                    // b_7  = 0.0
    if ((float)(lo + 4) * 0.125f - 1.0f < x) lo += 4;        // b_{lo+3}
    if ((float)(lo + 2) * 0.125f - 1.0f < x) lo += 2;        // b_{lo+1}
    if ((float)(lo + 1) * 0.125f - 1.0f < x) lo += 1;        // b_{lo}
    return lo;                                               // in [0, 15]
}

__device__ __forceinline__ int bin3(float r, float g, float b) {
    return bin16(r) + 16 * bin16(g) + 256 * bin16(b);
}

__global__ __launch_bounds__(THREADS) void hist_kernel(
        const float* __restrict__ input,   // [8,3,HW]
        const float* __restrict__ style,   // [1,3,HW]
        int* __restrict__ ghist) {         // [NIMG, NBINS]
    __shared__ int lh[NBINS];              // 16 KB
    const int img = blockIdx.y;
    const float* base = (img < 8) ? (input + (size_t)img * 3 * HW) : style;

    for (int i = threadIdx.x; i < NBINS; i += THREADS) lh[i] = 0;
    __syncthreads();

    const float4* c0 = (const float4*)(base);
    const float4* c1 = (const float4*)(base + HW);
    const float4* c2 = (const float4*)(base + 2 * HW);
    const int start = blockIdx.x * F4_PER_BLOCK;

    for (int j = threadIdx.x; j < F4_PER_BLOCK; j += THREADS) {
        const int p = start + j;
        float4 r = c0[p];
        float4 g = c1[p];
        float4 b = c2[p];
        atomicAdd(&lh[bin3(r.x, g.x, b.x)], 1);
        atomicAdd(&lh[bin3(r.y, g.y, b.y)], 1);
        atomicAdd(&lh[bin3(r.z, g.z, b.z)], 1);
        atomicAdd(&lh[bin3(r.w, g.w, b.w)], 1);
    }
    __syncthreads();

    int* gh = ghist + (size_t)img * NBINS;
    for (int i = threadIdx.x; i < NBINS; i += THREADS) {
        const int v = lh[i];
        if (v) atomicAdd(&gh[i], v);   // device-scope by default; skip zeros
    }
}

// loss = (1 / (HW * 8 * NBINS)) * sum_{b,i} | c_b[i] - t[i] |   (integer-exact)
__global__ __launch_bounds__(1024) void loss_kernel(
        const int* __restrict__ ghist, float* __restrict__ out) {
    __shared__ long long part[16];
    const int* tgt = ghist + 8 * NBINS;
    long long acc = 0;
    for (int e = threadIdx.x; e < 8 * NBINS; e += 1024) {
        const int b = e >> 12;
        const int i = e & (NBINS - 1);
        const int d = ghist[b * NBINS + i] - tgt[i];
        acc += (d < 0) ? (long long)(-d) : (long long)d;
    }
    // wave-64 shuffle reduce
    for (int off = 32; off; off >>= 1) acc += __shfl_down(acc, off, 64);
    const int lane = threadIdx.x & 63;
    const int wv   = threadIdx.x >> 6;
    if (lane == 0) part[wv] = acc;
    __syncthreads();
    if (wv == 0) {
        long long t = (lane < 16) ? part[lane] : 0;
        for (int off = 8; off; off >>= 1) t += __shfl_down(t, off, 64);
        if (lane == 0) {
            out[0] = (float)((double)t / (1048576.0 * 32768.0));
        }
    }
}

extern "C" void kernel_launch(void* const* d_in, const int* in_sizes, int n_in,
                              void* d_out, int out_size, void* d_ws, size_t ws_size,
                              hipStream_t stream) {
    const float* input = (const float*)d_in[0];  // [8,3,1024,1024]
    const float* style = (const float*)d_in[1];  // [1,3,1024,1024]
    // d_in[2] = n_bins (16), hard-coded above.
    int* ghist = (int*)d_ws;                     // 9 * 4096 ints = 147456 B

    hipMemsetAsync(d_ws, 0, NIMG * NBINS * sizeof(int), stream);

    dim3 grid(BPI, NIMG);
    hipLaunchKernelGGL(hist_kernel, grid, dim3(THREADS), 0, stream,
                       input, style, ghist);
    hipLaunchKernelGGL(loss_kernel, dim3(1), dim3(1024), 0, stream,
                       ghist, (float*)d_out);
}